// Round 5
// baseline (93.337 us; speedup 1.0000x reference)
//
#include <hip/hip_runtime.h>

#ifndef __has_builtin
#define __has_builtin(x) 0
#endif
#if __has_builtin(__builtin_amdgcn_fdot2)
#define HAVE_FDOT2 1
#else
#define HAVE_FDOT2 0
#endif

typedef _Float16 f16;
typedef _Float16 f16x2 __attribute__((ext_vector_type(2)));
typedef _Float16 f16x8 __attribute__((ext_vector_type(8)));
typedef float    f32x4 __attribute__((ext_vector_type(4)));
typedef float    f32x2 __attribute__((ext_vector_type(2)));
typedef unsigned int u32x4 __attribute__((ext_vector_type(4)));

#define Bn 16
#define Cn 256
#define Hn 48
#define Wn 64
#define NDISP 21
#define SLAB 32768                      // bytes per (b,row) slab of in2, f16
#define WS_NEED ((size_t)Bn * Hn * SLAB)   // 25.2 MB

// ============================================================================
// Conversion kernel (in2 only): f32 [b][c][row][w] -> f16 ws slabs in
// MFMA-B-FRAGMENT order, so the main kernel's B loads are contiguous 16B/lane:
//   slab(b,row) offset = kc*8192 + par*4096 + ni*2048 + kk*1024 + g*256 + nl*16 + j*2
//   holds in2[b][c = kc*64 + kk*32 + g*8 + j][row][w = 2*(ni*16+nl) + par]
// ============================================================================
__global__ __launch_bounds__(256) void convert_kernel(const float* __restrict__ in2,
                                                      char* __restrict__ ws)
{
    int i = blockIdx.x;                         // 0..767
    int b = i / Hn, row = i % Hn;
    char* dslab = ws + (size_t)i * SLAB;
    int t  = threadIdx.x;
    int nl = t & 15, g = (t >> 4) & 3, kk = (t >> 6) & 1, ni = (t >> 7) & 1;
    int wq = ni * 16 + nl;                      // w' 0..31
    const float* srcb = in2 + ((size_t)b * Cn * Hn + row) * Wn;
    char* dbase = dslab + ni * 2048 + kk * 1024 + g * 256 + nl * 16;
    #pragma unroll
    for (int kc = 0; kc < 4; ++kc) {
        union { f16 h[8]; u32x4 u; } e0, e1;
        #pragma unroll
        for (int j = 0; j < 8; ++j) {
            int c = kc * 64 + kk * 32 + g * 8 + j;
            f32x2 v = *(const f32x2*)&srcb[(size_t)c * Hn * Wn + 2 * wq];
            e0.h[j] = (f16)v.x;                 // even w  (par 0)
            e1.h[j] = (f16)v.y;                 // odd  w  (par 1)
        }
        *(u32x4*)(dbase + kc * 8192)        = e0.u;
        *(u32x4*)(dbase + kc * 8192 + 4096) = e1.u;
    }
}

// ============================================================================
// Per-wave worker, specialized on gram count NG (1..3) so every array index is
// compile-time (no scratch). Register-only pipeline: flattened steps
// s = 0..4*NG-1, step -> (gi = s%NG, c = s/NG); 3-deep bf ring, distance-2
// prefetch; 16 MFMAs per step. No LDS staging, no barriers; stores only after
// the pipeline completes (no store-drain stalls inside the load pipeline).
// ============================================================================
template<int NG>
__device__ void corr_wave(const float* __restrict__ in1b,
                          const char*  __restrict__ wsb,
                          float* __restrict__ outb,
                          int h, int wv, int klo, int l, float* bounce)
{
    const int nl = l & 15;
    const int g  = l >> 4;

    // ---- A-fragments: direct f32 load + convert ----
    // af[p][mi][k8] elem j = (f16) in1[b][c = k8*32+g*8+j][h][w = 2*(mi*16+nl)+p]
    f16x8 af[2][2][8];
    #pragma unroll
    for (int mi = 0; mi < 2; ++mi) {
        const int w2 = 2 * (mi * 16 + nl);
        #pragma unroll
        for (int k = 0; k < 8; ++k) {
            #pragma unroll
            for (int j = 0; j < 8; ++j) {
                int c = k * 32 + g * 8 + j;
                f32x2 v = *(const f32x2*)&in1b[((size_t)c * Hn + h) * Wn + w2];
                af[0][mi][k][j] = (f16)v.x;
                af[1][mi][k][j] = (f16)v.y;
            }
        }
    }

    // ---- per-gram B base pointers (wave-uniform rows) ----
    const char* gsv[NG];
    #pragma unroll
    for (int gi = 0; gi < NG; ++gi) {
        int dy = wv + 8 * (klo + gi);
        int r  = h + 2 * dy - 20;               // guaranteed in [0,48)
        gsv[gi] = wsb + (size_t)r * SLAB + l * 16;
    }

    f32x4 acc[NG][2][2][2];                     // [gram][par][mi][ni]
    #pragma unroll
    for (int gi = 0; gi < NG; ++gi)
        #pragma unroll
        for (int p2 = 0; p2 < 2; ++p2)
            #pragma unroll
            for (int mi = 0; mi < 2; ++mi)
                #pragma unroll
                for (int ni = 0; ni < 2; ++ni)
                    acc[gi][p2][mi][ni] = (f32x4){0.f, 0.f, 0.f, 0.f};

    f16x8 bf[3][2][2][2];                       // [ring][par][ni][kk]
    const int NSTEP = 4 * NG;
    #pragma unroll
    for (int s = 0; s < NSTEP + 2; ++s) {
        if (s < NSTEP) {                        // issue loads for step s
            const int gi = s % NG, c = s / NG;
            const char* base = gsv[gi] + c * 8192;
            #pragma unroll
            for (int p2 = 0; p2 < 2; ++p2)
                #pragma unroll
                for (int ni = 0; ni < 2; ++ni)
                    #pragma unroll
                    for (int kk = 0; kk < 2; ++kk)
                        bf[s % 3][p2][ni][kk] =
                            *(const f16x8*)(base + p2 * 4096 + ni * 2048 + kk * 1024);
        }
        if (s >= 2) {                           // compute step s-2
            const int sc = s - 2;
            const int gi = sc % NG, c = sc / NG;
            #pragma unroll
            for (int kk = 0; kk < 2; ++kk)
                #pragma unroll
                for (int p2 = 0; p2 < 2; ++p2)
                    #pragma unroll
                    for (int mi = 0; mi < 2; ++mi)
                        #pragma unroll
                        for (int ni = 0; ni < 2; ++ni)
                            acc[gi][p2][mi][ni] = __builtin_amdgcn_mfma_f32_16x16x32_f16(
                                af[p2][mi][c * 2 + kk], bf[sc % 3][p2][ni][kk],
                                acc[gi][p2][mi][ni], 0, 0, 0);
        }
    }

    // ---- extraction via per-wave LDS bounce; asm barriers order the
    // zero-fill / scalar scatter / vector reads (TBAA won't) ----
    #pragma unroll
    for (int gi = 0; gi < NG; ++gi) {
        int dy = wv + 8 * (klo + gi);
        #pragma unroll
        for (int i2 = 0; i2 < 6; ++i2)
            *(f32x4*)((char*)bounce + i2 * 1024 + l * 16) = (f32x4){0.f, 0.f, 0.f, 0.f};
        asm volatile("" ::: "memory");
        #pragma unroll
        for (int p2 = 0; p2 < 2; ++p2)
            #pragma unroll
            for (int mi = 0; mi < 2; ++mi)
                #pragma unroll
                for (int ni = 0; ni < 2; ++ni)
                    #pragma unroll
                    for (int rr = 0; rr < 4; ++rr) {
                        int o = nl + ((ni - mi) << 4) - 4 * g - rr;   // dx - 10
                        if (o >= -10 && o <= 10) {
                            int m = mi * 16 + 4 * g + rr;
                            bounce[(o + 10) * 64 + 2 * m + p2] = acc[gi][p2][mi][ni][rr];
                        }
                    }
        asm volatile("" ::: "memory");
        #pragma unroll
        for (int i2 = 0; i2 < 6; ++i2) {
            int dxr = i2 * 4 + g;
            if (dxr < NDISP) {
                f32x4 v = *(f32x4*)&bounce[dxr * 64 + nl * 4];
                v = v * (1.0f / 256.0f);
                *(f32x4*)&outb[((size_t)(dy * NDISP + dxr) * Hn + h) * Wn + nl * 4] = v;
            }
        }
        asm volatile("" ::: "memory");          // bounce reused by next gram
    }
}

__global__ __launch_bounds__(512, 2) void corr_mfma(const float* __restrict__ in1,
                                                    const char* __restrict__ ws,
                                                    float* __restrict__ out)
{
    __shared__ float bounce[8][1536];           // 6 KB per wave (extraction only)
    const int tid = threadIdx.x;
    const int wv  = tid >> 6;
    const int l   = tid & 63;
    const int nl  = l & 15;
    const int g   = l >> 4;

    int bid = blockIdx.x;                       // bijective XCD swizzle (768 = 8*96)
    int sw  = (bid & 7) * 96 + (bid >> 3);
    int b = sw / Hn, h = sw % Hn;

    const float* in1b = in1 + (size_t)b * Cn * Hn * Wn;
    const char*  wsb  = ws  + (size_t)b * Hn * SLAB;
    float* outb = out + (size_t)b * (NDISP * NDISP) * Hn * Wn;

    // ---- zero planes for this wave's invalid dy (normal stores) ----
    {
        f32x4 z = {0.f, 0.f, 0.f, 0.f};
        for (int dy = wv; dy < NDISP; dy += 8) {
            int r = h + 2 * dy - 20;
            if (r < 0 || r >= Hn) {
                #pragma unroll
                for (int i2 = 0; i2 < 6; ++i2) {
                    int dxr = i2 * 4 + g;
                    if (dxr < NDISP)
                        *(f32x4*)&outb[((size_t)(dy * NDISP + dxr) * Hn + h) * Wn + nl * 4] = z;
                }
            }
        }
    }

    // ---- valid-dy range for this wave: dy = wv + 8k, k in [klo, khi] ----
    int t0  = 20 - h - 2 * wv;
    int klo = (t0 > 0) ? ((t0 + 15) >> 4) : 0;
    int khi = (67 - h - 2 * wv) >> 4;
    int kdy = (20 - wv) >> 3;
    if (kdy < khi) khi = kdy;
    int ng = khi - klo + 1;
    if (ng <= 0) return;

    float* bw = bounce[wv];
    if (ng >= 3)      corr_wave<3>(in1b, wsb, outb, h, wv, klo, l, bw);
    else if (ng == 2) corr_wave<2>(in1b, wsb, outb, h, wv, klo, l, bw);
    else              corr_wave<1>(in1b, wsb, outb, h, wv, klo, l, bw);
}

// ============================================================================
// Fallback (round-1 kernel, known-good) if ws_size is too small.
// ============================================================================
#define BDIM 384
#define C2T  8
#define NCHUNK 16
#define JJN  56
#define IN1_DW (2*128*32)
#define IN2_DW (128*JJN + 64)

__device__ __forceinline__ unsigned int packh2(float a, float b) {
    union { f16x2 h; unsigned int u; } u;
    u.h.x = (_Float16)a; u.h.y = (_Float16)b;
    return u.u;
}
__device__ __forceinline__ float dot2(unsigned int a, unsigned int b, float c) {
    union { unsigned int u; f16x2 h; } ua, ub;
    ua.u = a; ub.u = b;
#if HAVE_FDOT2
    return __builtin_amdgcn_fdot2(ua.h, ub.h, c, false);
#else
    return c + (float)ua.h.x * (float)ub.h.x + (float)ua.h.y * (float)ub.h.y;
#endif
}
__device__ __forceinline__ int in2row(int m) { return m * JJN + (((m >> 3) & 1) << 2); }

__global__ __launch_bounds__(BDIM, 3) void corr_fallback(
    const float* __restrict__ in1, const float* __restrict__ in2,
    float* __restrict__ out)
{
    __shared__ __align__(16) unsigned int s_in1[IN1_DW];
    __shared__ __align__(16) unsigned int s_in2[IN2_DW];
    const int tid = threadIdx.x;
    int bid = blockIdx.x;
    int sw  = (bid & 7) * 96 + (bid >> 3);
    const int b = sw / Hn;
    const int h = sw - b * Hn;
    int dylo = (h < 20) ? ((21 - h) >> 1) : 0;
    int dyhi = min(NDISP - 1, (67 - h) >> 1) + 1;
    const int V = dyhi - dylo;
    const int wg   = tid & 15;
    const int p    = wg & 1;
    const int widx = (wg >> 1) << 2;
    const int t2   = tid >> 4;
    const int dxg  = t2 % 3;
    const int slot = t2 / 3;
    const int dxb  = dxg << 3;
    const float* in1b = in1 + (size_t)b * Cn * Hn * Wn;
    const float* in2b = in2 + (size_t)b * Cn * Hn * Wn;
    float* outb = out + (size_t)b * (NDISP * NDISP) * Hn * Wn;
    {
        int nz = NDISP - V;
        for (int j = tid; j < nz * NDISP * Wn; j += BDIM) {
            int zi  = j / (NDISP * Wn);
            int rem = j - zi * (NDISP * Wn);
            int dy  = (zi < dylo) ? zi : (dyhi + (zi - dylo));
            int dx  = rem >> 6;
            int w   = rem & 63;
            outb[((size_t)(dy * NDISP + dx) * Hn + h) * Wn + w] = 0.0f;
        }
    }
    for (int i = tid; i < 64 * 128; i += BDIM) {
        int w  = i & 63;
        int c2 = i >> 6;
        float f0 = in1b[((size_t)(2 * c2)     * Hn + h) * Wn + w];
        float f1 = in1b[((size_t)(2 * c2 + 1) * Hn + h) * Wn + w];
        int pp = w & 1, wq = w >> 1;
        s_in1[(pp * 128 + c2) * 32 + wq] = packh2(f0, f1);
    }
    const int nR = (V + 7) >> 3;
    for (int round = 0; round < nR; ++round) {
        const int dy0   = dylo + (round << 3);
        const int mydy  = dy0 + slot;
        const bool valid = (mydy < dyhi);
        float acc[4][8];
        #pragma unroll
        for (int i = 0; i < 4; ++i)
            #pragma unroll
            for (int j = 0; j < 8; ++j) acc[i][j] = 0.0f;
        for (int ch = 0; ch < NCHUNK; ++ch) {
            const int c2b = ch * C2T;
            __syncthreads();
            for (int i = tid; i < 8 * 2 * C2T * 112 / 2; i += BDIM) {
                int jj2 = i % 112;
                int t   = i / 112;
                int pp  = jj2 & 1;
                int jj  = jj2 >> 1;
                int c2o = t % C2T;
                int sl  = t / C2T;
                int dy  = dy0 + sl;
                if (dy >= dyhi) continue;
                int w2  = jj2 - 20;
                unsigned int val = 0;
                if (w2 >= 0 && w2 < Wn) {
                    int rr = h + 2 * dy - 20;
                    int c = 2 * (c2b + c2o);
                    const float* srcp = &in2b[((size_t)c * Hn + rr) * Wn + w2];
                    val = packh2(srcp[0], srcp[Hn * Wn]);
                }
                s_in2[in2row((sl * 2 + pp) * C2T + c2o) + jj] = val;
            }
            __syncthreads();
            if (valid) {
                const int base1 = (p * 128 + c2b) * 32 + widx;
                #pragma unroll
                for (int c2o = 0; c2o < C2T; ++c2o) {
                    u32x4 a4 = *(const u32x4*)&s_in1[base1 + c2o * 32];
                    const unsigned int* vr =
                        &s_in2[in2row((slot * 2 + p) * C2T + c2o) + widx + dxb];
                    u32x4 v0 = *(const u32x4*)(vr);
                    u32x4 v1 = *(const u32x4*)(vr + 4);
                    u32x4 v2 = *(const u32x4*)(vr + 8);
                    unsigned int av[4]  = {a4.x, a4.y, a4.z, a4.w};
                    unsigned int vv[12] = {v0.x, v0.y, v0.z, v0.w,
                                           v1.x, v1.y, v1.z, v1.w,
                                           v2.x, v2.y, v2.z, v2.w};
                    #pragma unroll
                    for (int wi = 0; wi < 4; ++wi)
                        #pragma unroll
                        for (int di = 0; di < 8; ++di)
                            acc[wi][di] = dot2(av[wi], vv[wi + di], acc[wi][di]);
                }
            }
        }
        float* s_out = (float*)s_in2;
        for (int half = 0; half < 2; ++half) {
            __syncthreads();
            if (((slot >> 2) == half) && valid) {
                #pragma unroll
                for (int wi = 0; wi < 4; ++wi)
                    #pragma unroll
                    for (int di = 0; di < 8; ++di) {
                        int dx = dxb + di;
                        if (dx < NDISP) {
                            int w = p + ((widx + wi) << 1);
                            s_out[(((slot & 3) * NDISP + dx) << 6) + w] =
                                acc[wi][di] * (1.0f / 256.0f);
                        }
                    }
            }
            __syncthreads();
            int dyb = dy0 + (half << 2);
            for (int j = tid; j < 4 * NDISP * Wn; j += BDIM) {
                int s  = j / (NDISP * Wn);
                int dy = dyb + s;
                if (dy < dyhi) {
                    int rem = j - s * (NDISP * Wn);
                    int dx  = rem >> 6;
                    int w   = rem & 63;
                    outb[((size_t)(dy * NDISP + dx) * Hn + h) * Wn + w] = s_out[j];
                }
            }
        }
    }
}

extern "C" void kernel_launch(void* const* d_in, const int* in_sizes, int n_in,
                              void* d_out, int out_size, void* d_ws, size_t ws_size,
                              hipStream_t stream) {
    (void)in_sizes; (void)n_in; (void)out_size;
    const float* in1 = (const float*)d_in[0];
    const float* in2 = (const float*)d_in[1];
    float* out = (float*)d_out;
    if (ws_size >= WS_NEED) {
        convert_kernel<<<dim3(Bn * Hn), dim3(256), 0, stream>>>(in2, (char*)d_ws);
        corr_mfma<<<dim3(Bn * Hn), dim3(512), 0, stream>>>(in1, (const char*)d_ws, out);
    } else {
        corr_fallback<<<dim3(Bn * Hn), dim3(BDIM), 0, stream>>>(in1, in2, out);
    }
}

// Round 6
// 71.202 us; speedup vs baseline: 1.3109x; 1.3109x over previous
//
#include <hip/hip_runtime.h>

#ifndef __has_builtin
#define __has_builtin(x) 0
#endif
#if __has_builtin(__builtin_amdgcn_fdot2)
#define HAVE_FDOT2 1
#else
#define HAVE_FDOT2 0
#endif

typedef _Float16 f16;
typedef _Float16 f16x2 __attribute__((ext_vector_type(2)));
typedef _Float16 f16x8 __attribute__((ext_vector_type(8)));
typedef float    f32x4 __attribute__((ext_vector_type(4)));
typedef float    f32x2 __attribute__((ext_vector_type(2)));
typedef unsigned int u32x4 __attribute__((ext_vector_type(4)));

#define Bn 16
#define Cn 256
#define Hn 48
#define Wn 64
#define NDISP 21
#define SLAB 32768                      // bytes per (b,row) slab of in2, f16
#define WS_NEED ((size_t)Bn * Hn * SLAB)   // 25.2 MB

// ============================================================================
// Conversion kernel (in2 only): f32 [b][c][row][w] -> f16 ws slabs in
// MFMA-B-FRAGMENT order (verified R5), so main-kernel B loads are 16B/lane:
//   slab(b,row) offset = kc*8192 + par*4096 + ni*2048 + kk*1024 + g*256 + nl*16 + j*2
//   holds in2[b][c = kc*64 + kk*32 + g*8 + j][row][w = 2*(ni*16+nl) + par]
// ============================================================================
__global__ __launch_bounds__(256) void convert_kernel(const float* __restrict__ in2,
                                                      char* __restrict__ ws)
{
    int i = blockIdx.x;                         // 0..767
    int b = i / Hn, row = i % Hn;
    char* dslab = ws + (size_t)i * SLAB;
    int t  = threadIdx.x;
    int nl = t & 15, g = (t >> 4) & 3, kk = (t >> 6) & 1, ni = (t >> 7) & 1;
    int wq = ni * 16 + nl;                      // w' 0..31
    const float* srcb = in2 + ((size_t)b * Cn * Hn + row) * Wn;
    char* dbase = dslab + ni * 2048 + kk * 1024 + g * 256 + nl * 16;
    #pragma unroll
    for (int kc = 0; kc < 4; ++kc) {
        union { f16 h[8]; u32x4 u; } e0, e1;
        #pragma unroll
        for (int j = 0; j < 8; ++j) {
            int c = kc * 64 + kk * 32 + g * 8 + j;
            f32x2 v = *(const f32x2*)&srcb[(size_t)c * Hn * Wn + 2 * wq];
            e0.h[j] = (f16)v.x;                 // even w  (par 0)
            e1.h[j] = (f16)v.y;                 // odd  w  (par 1)
        }
        *(u32x4*)(dbase + kc * 8192)        = e0.u;
        *(u32x4*)(dbase + kc * 8192 + 4096) = e1.u;
    }
}

// ============================================================================
// Per-wave worker, specialized on gram count NG (1..3). Grams SEQUENTIAL
// (acc = 32 VGPR only); B in a 2-deep named register ring (64 VGPR), steps
// flattened s = gi*4+kc so next gram's prefetch overlaps extraction. A frags
// come from LDS (ds_read_b128, conflict-free). Everything statically indexed.
// ============================================================================
template<int NG>
__device__ void corr_wave(const char* __restrict__ wsb,
                          float* __restrict__ outb,
                          const char* a_lds,
                          int h, int wv, int klo, int l, float* bounce)
{
    const int nl = l & 15;
    const int g  = l >> 4;

    const char* gsv[NG];
    #pragma unroll
    for (int gi = 0; gi < NG; ++gi) {
        int dy = wv + 8 * (klo + gi);
        int r  = h + 2 * dy - 20;               // guaranteed in [0,48)
        gsv[gi] = wsb + (size_t)r * SLAB + l * 16;
    }
    const char* abase = a_lds + g * 256 + nl * 16;

    f16x8 bfA[8], bfB[8];                       // q = p2*4 + ni*2 + kk
    #pragma unroll
    for (int q = 0; q < 8; ++q)                 // prologue: step 0 -> bfA
        bfA[q] = *(const f16x8*)(gsv[0] + ((q >> 2) & 1) * 4096
                                         + ((q >> 1) & 1) * 2048 + (q & 1) * 1024);

    #pragma unroll
    for (int gi = 0; gi < NG; ++gi) {
        f32x4 acc[2][2][2];                     // [par][mi][ni]
        #pragma unroll
        for (int p2 = 0; p2 < 2; ++p2)
            #pragma unroll
            for (int mi = 0; mi < 2; ++mi)
                #pragma unroll
                for (int ni = 0; ni < 2; ++ni)
                    acc[p2][mi][ni] = (f32x4){0.f, 0.f, 0.f, 0.f};

        #pragma unroll
        for (int kc = 0; kc < 4; ++kc) {
            const int s = gi * 4 + kc;
            if (s + 1 < 4 * NG) {               // issue next step's 8 loads
                const int gn = (s + 1) >> 2, kn = (s + 1) & 3;
                const char* base = gsv[gn] + kn * 8192;
                f16x8* dst = ((s + 1) & 1) ? bfB : bfA;
                #pragma unroll
                for (int q = 0; q < 8; ++q)
                    dst[q] = *(const f16x8*)(base + ((q >> 2) & 1) * 4096
                                                   + ((q >> 1) & 1) * 2048 + (q & 1) * 1024);
            }
            const f16x8* cur = (s & 1) ? bfB : bfA;
            #pragma unroll
            for (int kk = 0; kk < 2; ++kk) {
                f16x8 a[2][2];                  // [p][mi], from LDS just-in-time
                #pragma unroll
                for (int p2 = 0; p2 < 2; ++p2)
                    #pragma unroll
                    for (int mi = 0; mi < 2; ++mi)
                        a[p2][mi] = *(const f16x8*)(abase
                                        + (((p2 * 2 + mi) * 8) + kc * 2 + kk) * 1024);
                #pragma unroll
                for (int p2 = 0; p2 < 2; ++p2)
                    #pragma unroll
                    for (int mi = 0; mi < 2; ++mi)
                        #pragma unroll
                        for (int ni = 0; ni < 2; ++ni)
                            acc[p2][mi][ni] = __builtin_amdgcn_mfma_f32_16x16x32_f16(
                                a[p2][mi], cur[p2 * 4 + ni * 2 + kk],
                                acc[p2][mi][ni], 0, 0, 0);
            }
        }

        // ---- extraction via per-wave LDS bounce (verified R3/R5); asm
        // barriers order zero-fill / scalar scatter / vector reads ----
        int dy = wv + 8 * (klo + gi);
        #pragma unroll
        for (int i2 = 0; i2 < 6; ++i2)
            *(f32x4*)((char*)bounce + i2 * 1024 + l * 16) = (f32x4){0.f, 0.f, 0.f, 0.f};
        asm volatile("" ::: "memory");
        #pragma unroll
        for (int p2 = 0; p2 < 2; ++p2)
            #pragma unroll
            for (int mi = 0; mi < 2; ++mi)
                #pragma unroll
                for (int ni = 0; ni < 2; ++ni)
                    #pragma unroll
                    for (int rr = 0; rr < 4; ++rr) {
                        int o = nl + ((ni - mi) << 4) - 4 * g - rr;   // dx - 10
                        if (o >= -10 && o <= 10) {
                            int m = mi * 16 + 4 * g + rr;
                            bounce[(o + 10) * 64 + 2 * m + p2] = acc[p2][mi][ni][rr];
                        }
                    }
        asm volatile("" ::: "memory");
        #pragma unroll
        for (int i2 = 0; i2 < 6; ++i2) {
            int dxr = i2 * 4 + g;
            if (dxr < NDISP) {
                f32x4 v = *(f32x4*)&bounce[dxr * 64 + nl * 4];
                v = v * (1.0f / 256.0f);
                *(f32x4*)&outb[((size_t)(dy * NDISP + dxr) * Hn + h) * Wn + nl * 4] = v;
            }
        }
        asm volatile("" ::: "memory");          // bounce reused by next gram
    }
}

__global__ __launch_bounds__(512, 4) void corr_mfma(const float* __restrict__ in1,
                                                    const char* __restrict__ ws,
                                                    float* __restrict__ out)
{
    __shared__ char  a_lds[32768];              // A fragments, block-shared
    __shared__ float bounce[8][1536];           // 6 KB per wave (extraction)
    const int tid = threadIdx.x;
    const int wv  = tid >> 6;
    const int l   = tid & 63;
    const int nl  = l & 15;
    const int g   = l >> 4;

    int bid = blockIdx.x;                       // bijective XCD swizzle (768 = 8*96)
    int sw  = (bid & 7) * 96 + (bid >> 3);
    int b = sw / Hn, h = sw % Hn;

    const float* in1b = in1 + (size_t)b * Cn * Hn * Wn;
    const char*  wsb  = ws  + (size_t)b * Hn * SLAB;
    float* outb = out + (size_t)b * (NDISP * NDISP) * Hn * Wn;

    // ---- A fill: each of 512 threads owns (k8,g,nl), makes 4 fragments ----
    // a_lds offset(p,mi,k8,g,nl) = ((p*2+mi)*8+k8)*1024 + g*256 + nl*16,
    // elem j = (f16) in1[b][c=k8*32+g*8+j][h][w=2*(mi*16+nl)+p]
    {
        int fnl = tid & 15, fg = (tid >> 4) & 3, fk8 = (tid >> 6) & 7;
        union { f16 hh[8]; u32x4 u; } e[2][2];  // [p][mi]
        #pragma unroll
        for (int mi = 0; mi < 2; ++mi) {
            int w2 = 2 * (mi * 16 + fnl);
            #pragma unroll
            for (int j = 0; j < 8; ++j) {
                int c = fk8 * 32 + fg * 8 + j;
                f32x2 v = *(const f32x2*)&in1b[((size_t)c * Hn + h) * Wn + w2];
                e[0][mi].hh[j] = (f16)v.x;
                e[1][mi].hh[j] = (f16)v.y;
            }
        }
        #pragma unroll
        for (int p = 0; p < 2; ++p)
            #pragma unroll
            for (int mi = 0; mi < 2; ++mi)
                *(u32x4*)(a_lds + (((p * 2 + mi) * 8 + fk8) * 64 + fg * 16 + fnl) * 16)
                    = e[p][mi].u;
    }

    // ---- zero planes for this wave's invalid dy ----
    {
        f32x4 z = {0.f, 0.f, 0.f, 0.f};
        for (int dy = wv; dy < NDISP; dy += 8) {
            int r = h + 2 * dy - 20;
            if (r < 0 || r >= Hn) {
                #pragma unroll
                for (int i2 = 0; i2 < 6; ++i2) {
                    int dxr = i2 * 4 + g;
                    if (dxr < NDISP)
                        *(f32x4*)&outb[((size_t)(dy * NDISP + dxr) * Hn + h) * Wn + nl * 4] = z;
                }
            }
        }
    }

    __syncthreads();                            // a_lds visible to all waves

    // ---- valid-dy range for this wave: dy = wv + 8k, k in [klo, khi] ----
    int t0  = 20 - h - 2 * wv;
    int klo = (t0 > 0) ? ((t0 + 15) >> 4) : 0;
    int khi = (67 - h - 2 * wv) >> 4;
    int kdy = (20 - wv) >> 3;
    if (kdy < khi) khi = kdy;
    int ng = khi - klo + 1;
    if (ng <= 0) return;

    float* bw = bounce[wv];
    if (ng >= 3)      corr_wave<3>(wsb, outb, a_lds, h, wv, klo, l, bw);
    else if (ng == 2) corr_wave<2>(wsb, outb, a_lds, h, wv, klo, l, bw);
    else              corr_wave<1>(wsb, outb, a_lds, h, wv, klo, l, bw);
}

// ============================================================================
// Fallback (round-1 kernel, known-good) if ws_size is too small.
// ============================================================================
#define BDIM 384
#define C2T  8
#define NCHUNK 16
#define JJN  56
#define IN1_DW (2*128*32)
#define IN2_DW (128*JJN + 64)

__device__ __forceinline__ unsigned int packh2(float a, float b) {
    union { f16x2 h; unsigned int u; } u;
    u.h.x = (_Float16)a; u.h.y = (_Float16)b;
    return u.u;
}
__device__ __forceinline__ float dot2(unsigned int a, unsigned int b, float c) {
    union { unsigned int u; f16x2 h; } ua, ub;
    ua.u = a; ub.u = b;
#if HAVE_FDOT2
    return __builtin_amdgcn_fdot2(ua.h, ub.h, c, false);
#else
    return c + (float)ua.h.x * (float)ub.h.x + (float)ua.h.y * (float)ub.h.y;
#endif
}
__device__ __forceinline__ int in2row(int m) { return m * JJN + (((m >> 3) & 1) << 2); }

__global__ __launch_bounds__(BDIM, 3) void corr_fallback(
    const float* __restrict__ in1, const float* __restrict__ in2,
    float* __restrict__ out)
{
    __shared__ __align__(16) unsigned int s_in1[IN1_DW];
    __shared__ __align__(16) unsigned int s_in2[IN2_DW];
    const int tid = threadIdx.x;
    int bid = blockIdx.x;
    int sw  = (bid & 7) * 96 + (bid >> 3);
    const int b = sw / Hn;
    const int h = sw - b * Hn;
    int dylo = (h < 20) ? ((21 - h) >> 1) : 0;
    int dyhi = min(NDISP - 1, (67 - h) >> 1) + 1;
    const int V = dyhi - dylo;
    const int wg   = tid & 15;
    const int p    = wg & 1;
    const int widx = (wg >> 1) << 2;
    const int t2   = tid >> 4;
    const int dxg  = t2 % 3;
    const int slot = t2 / 3;
    const int dxb  = dxg << 3;
    const float* in1b = in1 + (size_t)b * Cn * Hn * Wn;
    const float* in2b = in2 + (size_t)b * Cn * Hn * Wn;
    float* outb = out + (size_t)b * (NDISP * NDISP) * Hn * Wn;
    {
        int nz = NDISP - V;
        for (int j = tid; j < nz * NDISP * Wn; j += BDIM) {
            int zi  = j / (NDISP * Wn);
            int rem = j - zi * (NDISP * Wn);
            int dy  = (zi < dylo) ? zi : (dyhi + (zi - dylo));
            int dx  = rem >> 6;
            int w   = rem & 63;
            outb[((size_t)(dy * NDISP + dx) * Hn + h) * Wn + w] = 0.0f;
        }
    }
    for (int i = tid; i < 64 * 128; i += BDIM) {
        int w  = i & 63;
        int c2 = i >> 6;
        float f0 = in1b[((size_t)(2 * c2)     * Hn + h) * Wn + w];
        float f1 = in1b[((size_t)(2 * c2 + 1) * Hn + h) * Wn + w];
        int pp = w & 1, wq = w >> 1;
        s_in1[(pp * 128 + c2) * 32 + wq] = packh2(f0, f1);
    }
    const int nR = (V + 7) >> 3;
    for (int round = 0; round < nR; ++round) {
        const int dy0   = dylo + (round << 3);
        const int mydy  = dy0 + slot;
        const bool valid = (mydy < dyhi);
        float acc[4][8];
        #pragma unroll
        for (int i = 0; i < 4; ++i)
            #pragma unroll
            for (int j = 0; j < 8; ++j) acc[i][j] = 0.0f;
        for (int ch = 0; ch < NCHUNK; ++ch) {
            const int c2b = ch * C2T;
            __syncthreads();
            for (int i = tid; i < 8 * 2 * C2T * 112 / 2; i += BDIM) {
                int jj2 = i % 112;
                int t   = i / 112;
                int pp  = jj2 & 1;
                int jj  = jj2 >> 1;
                int c2o = t % C2T;
                int sl  = t / C2T;
                int dy  = dy0 + sl;
                if (dy >= dyhi) continue;
                int w2  = jj2 - 20;
                unsigned int val = 0;
                if (w2 >= 0 && w2 < Wn) {
                    int rr = h + 2 * dy - 20;
                    int c = 2 * (c2b + c2o);
                    const float* srcp = &in2b[((size_t)c * Hn + rr) * Wn + w2];
                    val = packh2(srcp[0], srcp[Hn * Wn]);
                }
                s_in2[in2row((sl * 2 + pp) * C2T + c2o) + jj] = val;
            }
            __syncthreads();
            if (valid) {
                const int base1 = (p * 128 + c2b) * 32 + widx;
                #pragma unroll
                for (int c2o = 0; c2o < C2T; ++c2o) {
                    u32x4 a4 = *(const u32x4*)&s_in1[base1 + c2o * 32];
                    const unsigned int* vr =
                        &s_in2[in2row((slot * 2 + p) * C2T + c2o) + widx + dxb];
                    u32x4 v0 = *(const u32x4*)(vr);
                    u32x4 v1 = *(const u32x4*)(vr + 4);
                    u32x4 v2 = *(const u32x4*)(vr + 8);
                    unsigned int av[4]  = {a4.x, a4.y, a4.z, a4.w};
                    unsigned int vv[12] = {v0.x, v0.y, v0.z, v0.w,
                                           v1.x, v1.y, v1.z, v1.w,
                                           v2.x, v2.y, v2.z, v2.w};
                    #pragma unroll
                    for (int wi = 0; wi < 4; ++wi)
                        #pragma unroll
                        for (int di = 0; di < 8; ++di)
                            acc[wi][di] = dot2(av[wi], vv[wi + di], acc[wi][di]);
                }
            }
        }
        float* s_out = (float*)s_in2;
        for (int half = 0; half < 2; ++half) {
            __syncthreads();
            if (((slot >> 2) == half) && valid) {
                #pragma unroll
                for (int wi = 0; wi < 4; ++wi)
                    #pragma unroll
                    for (int di = 0; di < 8; ++di) {
                        int dx = dxb + di;
                        if (dx < NDISP) {
                            int w = p + ((widx + wi) << 1);
                            s_out[(((slot & 3) * NDISP + dx) << 6) + w] =
                                acc[wi][di] * (1.0f / 256.0f);
                        }
                    }
            }
            __syncthreads();
            int dyb = dy0 + (half << 2);
            for (int j = tid; j < 4 * NDISP * Wn; j += BDIM) {
                int s  = j / (NDISP * Wn);
                int dy = dyb + s;
                if (dy < dyhi) {
                    int rem = j - s * (NDISP * Wn);
                    int dx  = rem >> 6;
                    int w   = rem & 63;
                    outb[((size_t)(dy * NDISP + dx) * Hn + h) * Wn + w] = s_out[j];
                }
            }
        }
    }
}

extern "C" void kernel_launch(void* const* d_in, const int* in_sizes, int n_in,
                              void* d_out, int out_size, void* d_ws, size_t ws_size,
                              hipStream_t stream) {
    (void)in_sizes; (void)n_in; (void)out_size;
    const float* in1 = (const float*)d_in[0];
    const float* in2 = (const float*)d_in[1];
    float* out = (float*)d_out;
    if (ws_size >= WS_NEED) {
        convert_kernel<<<dim3(Bn * Hn), dim3(256), 0, stream>>>(in2, (char*)d_ws);
        corr_mfma<<<dim3(Bn * Hn), dim3(512), 0, stream>>>(in1, (const char*)d_ws, out);
    } else {
        corr_fallback<<<dim3(Bn * Hn), dim3(BDIM), 0, stream>>>(in1, in2, out);
    }
}

// Round 7
// 67.423 us; speedup vs baseline: 1.3843x; 1.0560x over previous
//
#include <hip/hip_runtime.h>

#ifndef __has_builtin
#define __has_builtin(x) 0
#endif
#if __has_builtin(__builtin_amdgcn_fdot2)
#define HAVE_FDOT2 1
#else
#define HAVE_FDOT2 0
#endif

#define AS1q __attribute__((address_space(1)))
#define AS3q __attribute__((address_space(3)))

typedef _Float16 f16;
typedef _Float16 f16x2 __attribute__((ext_vector_type(2)));
typedef _Float16 f16x8 __attribute__((ext_vector_type(8)));
typedef float    f32x4 __attribute__((ext_vector_type(4)));
typedef float    f32x2 __attribute__((ext_vector_type(2)));
typedef unsigned int u32x4 __attribute__((ext_vector_type(4)));

#define Bn 16
#define Cn 256
#define Hn 48
#define Wn 64
#define NDISP 21
#define SLAB 32768                      // bytes per (b,row) slab of in2, f16
#define WS_NEED ((size_t)Bn * Hn * SLAB)   // 25.2 MB

// ============================================================================
// Conversion kernel (in2 only), VERIFIED R5/R6: f32 [b][c][row][w] -> f16 ws
// slabs in MFMA-B-FRAGMENT order:
//   slab(b,row) offset = kc*8192 + par*4096 + ni*2048 + kk*1024 + g*256 + nl*16 + j*2
//   holds in2[b][c = kc*64 + kk*32 + g*8 + j][row][w = 2*(ni*16+nl) + par]
// ============================================================================
__global__ __launch_bounds__(256) void convert_kernel(const float* __restrict__ in2,
                                                      char* __restrict__ ws)
{
    int i = blockIdx.x;                         // 0..767
    int b = i / Hn, row = i % Hn;
    char* dslab = ws + (size_t)i * SLAB;
    int t  = threadIdx.x;
    int nl = t & 15, g = (t >> 4) & 3, kk = (t >> 6) & 1, ni = (t >> 7) & 1;
    int wq = ni * 16 + nl;                      // w' 0..31
    const float* srcb = in2 + ((size_t)b * Cn * Hn + row) * Wn;
    char* dbase = dslab + ni * 2048 + kk * 1024 + g * 256 + nl * 16;
    #pragma unroll
    for (int kc = 0; kc < 4; ++kc) {
        union { f16 h[8]; u32x4 u; } e0, e1;
        #pragma unroll
        for (int j = 0; j < 8; ++j) {
            int c = kc * 64 + kk * 32 + g * 8 + j;
            f32x2 v = *(const f32x2*)&srcb[(size_t)c * Hn * Wn + 2 * wq];
            e0.h[j] = (f16)v.x;                 // even w  (par 0)
            e1.h[j] = (f16)v.y;                 // odd  w  (par 1)
        }
        *(u32x4*)(dbase + kc * 8192)        = e0.u;
        *(u32x4*)(dbase + kc * 8192 + 4096) = e1.u;
    }
}

// ============================================================================
// Main kernel V7: block = (b, parity pi, tile of 4 same-parity h's); 192 blocks.
// Rows r = h+2dy-20 (all ≡ pi mod 2, ≤22 per block) are staged ONCE (full-K
// 32KB slab -> LDS ring of 4 slots, global_load_lds, depth-3 prefetch,
// uniform vmcnt(12) with dummy-clamped tail stages). Per row-step, 8 waves =
// (h-index i, w-parity p2) each compute ONE full-K parity-Gram (acc 16 VGPR,
// A frags 64 VGPR preloaded), scatter the |dx-10|<=10 band into a pair-shared
// XOR-swizzled bounce plane, then co-store coalesced f32x4 planes.
// ============================================================================
__device__ __forceinline__ void stage4(const char* slab, char* slot, int off0, int l16)
{
    #pragma unroll
    for (int q = 0; q < 4; ++q) {
        int off = off0 + q * 1024 + l16;
        __builtin_amdgcn_global_load_lds((const AS1q void*)(slab + off),
                                         (AS3q void*)(slot + off), 16, 0, 0);
    }
}

__global__ __launch_bounds__(512, 2) void corr_mfma(const float* __restrict__ in1,
                                                    const char* __restrict__ ws,
                                                    float* __restrict__ out)
{
    __shared__ char  Bring[4][32768];           // row-slab ring (128 KB)
    __shared__ float bounce[4][1344];           // per-h [21 dx][64 w] planes (21 KB)

    const int tid = threadIdx.x;
    const int wv  = tid >> 6;
    const int l   = tid & 63;
    const int nl  = l & 15;
    const int g   = l >> 4;
    const int i   = wv >> 1;                    // h index 0..3
    const int p2  = wv & 1;                     // w parity

    int bid = blockIdx.x;
    int swz = (bid & 7) * 24 + (bid >> 3);      // 192 = 8*24, bijective XCD swizzle
    int b   = swz / 12;
    int rem = swz - b * 12;
    int pi  = rem / 6;
    int t   = rem - pi * 6;
    int h0  = pi + 8 * t;
    int h   = h0 + 2 * i;

    const float* in1b = in1 + (size_t)b * Cn * Hn * Wn;
    const char*  wsb  = ws  + (size_t)b * Hn * SLAB;
    float* outb = out + (size_t)b * (NDISP * NDISP) * Hn * Wn;

    int rlo = (h0 >= 20) ? (h0 - 20) : pi;      // parity-preserving clip
    int rhi = min(h0 + 26, 46 + pi);
    int NR  = ((rhi - rlo) >> 1) + 1;           // 14..22
    int dybase = (rlo - h0 + 20) >> 1;          // dy(s,i) = s + dybase - i

    // ---- zero invalid-dy planes for this h (dx split by parity wave) ----
    {
        int dylo = (h < 20) ? ((21 - h) >> 1) : 0;
        int dyhi = min(NDISP, ((67 - h) >> 1) + 1);
        f32x4 z = {0.f, 0.f, 0.f, 0.f};
        for (int dy = 0; dy < NDISP; ++dy) {
            if (dy >= dylo && dy < dyhi) continue;
            #pragma unroll
            for (int q = 0; q < 3; ++q) {
                int dx = p2 * 12 + q * 4 + g;
                if (dx < NDISP)
                    *(f32x4*)&outb[((size_t)(dy * NDISP + dx) * Hn + h) * Wn + nl * 4] = z;
            }
        }
    }

    // ---- A preload (VERIFIED frag contract): af[mi][k8] elem j =
    //      f16(in1[c=k8*32+g*8+j][h][w=2*(mi*16+nl)+p2]) ----
    f16x8 af[2][8];
    #pragma unroll
    for (int mi = 0; mi < 2; ++mi) {
        int wcol = 2 * (mi * 16 + nl) + p2;
        #pragma unroll
        for (int k8 = 0; k8 < 8; ++k8)
            #pragma unroll
            for (int j = 0; j < 8; ++j) {
                int c = k8 * 32 + g * 8 + j;
                af[mi][k8][j] = (f16)in1b[((size_t)c * Hn + h) * Wn + wcol];
            }
    }

    // ---- zero bounce planes ----
    {
        f32x4* bz = (f32x4*)&bounce[0][0];
        #pragma unroll
        for (int q = 0; q < 3; ++q) {
            int idx = q * 512 + tid;
            if (idx < 4 * 1344 / 4) bz[idx] = (f32x4){0.f, 0.f, 0.f, 0.f};
        }
    }

    asm volatile("s_waitcnt vmcnt(0)" ::: "memory");   // A-loads done; vmem queue known

    const int off0 = wv * 4096;                 // this wave's 4 KB staging share
    const int l16  = l * 16;

    // ---- prologue: stage rows 0..2 into slots 0..2 ----
    #pragma unroll
    for (int ps = 0; ps < 3; ++ps)
        stage4(wsb + (size_t)(rlo + 2 * min(ps, NR - 1)) * SLAB, &Bring[ps][0], off0, l16);

    for (int s = 0; s < NR; ++s) {
        // phase A: stage row s+3 (clamped dummy at tail keeps vmcnt uniform)
        stage4(wsb + (size_t)(rlo + 2 * min(s + 3, NR - 1)) * SLAB,
               &Bring[(s + 3) & 3][0], off0, l16);
        // 12 loads newer than row-s's 4 -> vmcnt(12) proves row s arrived
        // (loads retire in order; stores only inflate the count = safe).
        asm volatile("s_waitcnt vmcnt(12)" ::: "memory");
        __syncthreads();

        int dy = s + dybase - i;
        bool valid = (unsigned)dy < (unsigned)NDISP;
        const char* slot = &Bring[s & 3][0];
        float* bp = &bounce[i][0];

        if (valid) {
            f32x4 acc[2][2];                    // [mi][ni]
            acc[0][0] = acc[0][1] = acc[1][0] = acc[1][1] = (f32x4){0.f, 0.f, 0.f, 0.f};
            #pragma unroll
            for (int k8 = 0; k8 < 8; ++k8) {
                const char* kb = slot + (k8 >> 1) * 8192 + (k8 & 1) * 1024 + p2 * 4096;
                f16x8 b0 = *(const f16x8*)(kb + l16);
                f16x8 b1 = *(const f16x8*)(kb + 2048 + l16);
                #pragma unroll
                for (int mi = 0; mi < 2; ++mi) {
                    acc[mi][0] = __builtin_amdgcn_mfma_f32_16x16x32_f16(af[mi][k8], b0, acc[mi][0], 0, 0, 0);
                    acc[mi][1] = __builtin_amdgcn_mfma_f32_16x16x32_f16(af[mi][k8], b1, acc[mi][1], 0, 0, 0);
                }
            }
            // scatter diag band into pair-shared bounce (w XOR-swizzled per dx)
            #pragma unroll
            for (int mi = 0; mi < 2; ++mi)
                #pragma unroll
                for (int ni = 0; ni < 2; ++ni)
                    #pragma unroll
                    for (int rr = 0; rr < 4; ++rr) {
                        int o = nl + ((ni - mi) << 4) - 4 * g - rr;   // dx - 10
                        if (o >= -10 && o <= 10) {
                            int m  = mi * 16 + 4 * g + rr;
                            int dx = o + 10;
                            int wsw = (2 * m + p2) ^ ((dx & 7) << 3);
                            bp[dx * 64 + wsw] = acc[mi][ni][rr];
                        }
                    }
        }
        __syncthreads();                        // pair's scatter complete; ring slot free
        if (valid) {
            #pragma unroll
            for (int q = 0; q < 3; ++q) {
                int dx = p2 * 12 + q * 4 + g;
                if (dx < NDISP) {
                    int wb = (4 * nl) ^ ((dx & 7) << 3);
                    f32x4 v = *(f32x4*)&bp[dx * 64 + wb];
                    v = v * (1.0f / 256.0f);
                    *(f32x4*)&outb[((size_t)(dy * NDISP + dx) * Hn + h) * Wn + nl * 4] = v;
                    *(f32x4*)&bp[dx * 64 + wb] = (f32x4){0.f, 0.f, 0.f, 0.f};  // re-zero
                }
            }
        }
    }
}

// ============================================================================
// Fallback (round-1 kernel, known-good) if ws_size is too small.
// ============================================================================
#define BDIM 384
#define C2T  8
#define NCHUNK 16
#define JJN  56
#define IN1_DW (2*128*32)
#define IN2_DW (128*JJN + 64)

__device__ __forceinline__ unsigned int packh2(float a, float b) {
    union { f16x2 h; unsigned int u; } u;
    u.h.x = (_Float16)a; u.h.y = (_Float16)b;
    return u.u;
}
__device__ __forceinline__ float dot2(unsigned int a, unsigned int b, float c) {
    union { unsigned int u; f16x2 h; } ua, ub;
    ua.u = a; ub.u = b;
#if HAVE_FDOT2
    return __builtin_amdgcn_fdot2(ua.h, ub.h, c, false);
#else
    return c + (float)ua.h.x * (float)ub.h.x + (float)ua.h.y * (float)ub.h.y;
#endif
}
__device__ __forceinline__ int in2row(int m) { return m * JJN + (((m >> 3) & 1) << 2); }

__global__ __launch_bounds__(BDIM, 3) void corr_fallback(
    const float* __restrict__ in1, const float* __restrict__ in2,
    float* __restrict__ out)
{
    __shared__ __align__(16) unsigned int s_in1[IN1_DW];
    __shared__ __align__(16) unsigned int s_in2[IN2_DW];
    const int tid = threadIdx.x;
    int bid = blockIdx.x;
    int sw  = (bid & 7) * 96 + (bid >> 3);
    const int b = sw / Hn;
    const int h = sw - b * Hn;
    int dylo = (h < 20) ? ((21 - h) >> 1) : 0;
    int dyhi = min(NDISP - 1, (67 - h) >> 1) + 1;
    const int V = dyhi - dylo;
    const int wg   = tid & 15;
    const int p    = wg & 1;
    const int widx = (wg >> 1) << 2;
    const int t2   = tid >> 4;
    const int dxg  = t2 % 3;
    const int slot = t2 / 3;
    const int dxb  = dxg << 3;
    const float* in1b = in1 + (size_t)b * Cn * Hn * Wn;
    const float* in2b = in2 + (size_t)b * Cn * Hn * Wn;
    float* outb = out + (size_t)b * (NDISP * NDISP) * Hn * Wn;
    {
        int nz = NDISP - V;
        for (int j = tid; j < nz * NDISP * Wn; j += BDIM) {
            int zi  = j / (NDISP * Wn);
            int rem = j - zi * (NDISP * Wn);
            int dy  = (zi < dylo) ? zi : (dyhi + (zi - dylo));
            int dx  = rem >> 6;
            int w   = rem & 63;
            outb[((size_t)(dy * NDISP + dx) * Hn + h) * Wn + w] = 0.0f;
        }
    }
    for (int i = tid; i < 64 * 128; i += BDIM) {
        int w  = i & 63;
        int c2 = i >> 6;
        float f0 = in1b[((size_t)(2 * c2)     * Hn + h) * Wn + w];
        float f1 = in1b[((size_t)(2 * c2 + 1) * Hn + h) * Wn + w];
        int pp = w & 1, wq = w >> 1;
        s_in1[(pp * 128 + c2) * 32 + wq] = packh2(f0, f1);
    }
    const int nR = (V + 7) >> 3;
    for (int round = 0; round < nR; ++round) {
        const int dy0   = dylo + (round << 3);
        const int mydy  = dy0 + slot;
        const bool valid = (mydy < dyhi);
        float acc[4][8];
        #pragma unroll
        for (int i = 0; i < 4; ++i)
            #pragma unroll
            for (int j = 0; j < 8; ++j) acc[i][j] = 0.0f;
        for (int ch = 0; ch < NCHUNK; ++ch) {
            const int c2b = ch * C2T;
            __syncthreads();
            for (int i = tid; i < 8 * 2 * C2T * 112 / 2; i += BDIM) {
                int jj2 = i % 112;
                int t   = i / 112;
                int pp  = jj2 & 1;
                int jj  = jj2 >> 1;
                int c2o = t % C2T;
                int sl  = t / C2T;
                int dy  = dy0 + sl;
                if (dy >= dyhi) continue;
                int w2  = jj2 - 20;
                unsigned int val = 0;
                if (w2 >= 0 && w2 < Wn) {
                    int rr = h + 2 * dy - 20;
                    int c = 2 * (c2b + c2o);
                    const float* srcp = &in2b[((size_t)c * Hn + rr) * Wn + w2];
                    val = packh2(srcp[0], srcp[Hn * Wn]);
                }
                s_in2[in2row((sl * 2 + pp) * C2T + c2o) + jj] = val;
            }
            __syncthreads();
            if (valid) {
                const int base1 = (p * 128 + c2b) * 32 + widx;
                #pragma unroll
                for (int c2o = 0; c2o < C2T; ++c2o) {
                    u32x4 a4 = *(const u32x4*)&s_in1[base1 + c2o * 32];
                    const unsigned int* vr =
                        &s_in2[in2row((slot * 2 + p) * C2T + c2o) + widx + dxb];
                    u32x4 v0 = *(const u32x4*)(vr);
                    u32x4 v1 = *(const u32x4*)(vr + 4);
                    u32x4 v2 = *(const u32x4*)(vr + 8);
                    unsigned int av[4]  = {a4.x, a4.y, a4.z, a4.w};
                    unsigned int vv[12] = {v0.x, v0.y, v0.z, v0.w,
                                           v1.x, v1.y, v1.z, v1.w,
                                           v2.x, v2.y, v2.z, v2.w};
                    #pragma unroll
                    for (int wi = 0; wi < 4; ++wi)
                        #pragma unroll
                        for (int di = 0; di < 8; ++di)
                            acc[wi][di] = dot2(av[wi], vv[wi + di], acc[wi][di]);
                }
            }
        }
        float* s_out = (float*)s_in2;
        for (int half = 0; half < 2; ++half) {
            __syncthreads();
            if (((slot >> 2) == half) && valid) {
                #pragma unroll
                for (int wi = 0; wi < 4; ++wi)
                    #pragma unroll
                    for (int di = 0; di < 8; ++di) {
                        int dx = dxb + di;
                        if (dx < NDISP) {
                            int w = p + ((widx + wi) << 1);
                            s_out[(((slot & 3) * NDISP + dx) << 6) + w] =
                                acc[wi][di] * (1.0f / 256.0f);
                        }
                    }
            }
            __syncthreads();
            int dyb = dy0 + (half << 2);
            for (int j = tid; j < 4 * NDISP * Wn; j += BDIM) {
                int s  = j / (NDISP * Wn);
                int dy = dyb + s;
                if (dy < dyhi) {
                    int rem = j - s * (NDISP * Wn);
                    int dx  = rem >> 6;
                    int w   = rem & 63;
                    outb[((size_t)(dy * NDISP + dx) * Hn + h) * Wn + w] = s_out[j];
                }
            }
        }
    }
}

extern "C" void kernel_launch(void* const* d_in, const int* in_sizes, int n_in,
                              void* d_out, int out_size, void* d_ws, size_t ws_size,
                              hipStream_t stream) {
    (void)in_sizes; (void)n_in; (void)out_size;
    const float* in1 = (const float*)d_in[0];
    const float* in2 = (const float*)d_in[1];
    float* out = (float*)d_out;
    if (ws_size >= WS_NEED) {
        convert_kernel<<<dim3(Bn * Hn), dim3(256), 0, stream>>>(in2, (char*)d_ws);
        corr_mfma<<<dim3(192), dim3(512), 0, stream>>>(in1, (const char*)d_ws, out);
    } else {
        corr_fallback<<<dim3(Bn * Hn), dim3(BDIM), 0, stream>>>(in1, in2, out);
    }
}

// Round 10
// 64.887 us; speedup vs baseline: 1.4385x; 1.0391x over previous
//
#include <hip/hip_runtime.h>

#ifndef __has_builtin
#define __has_builtin(x) 0
#endif
#if __has_builtin(__builtin_amdgcn_fdot2)
#define HAVE_FDOT2 1
#else
#define HAVE_FDOT2 0
#endif

#define AS1q __attribute__((address_space(1)))
#define AS3q __attribute__((address_space(3)))

typedef _Float16 f16;
typedef _Float16 f16x2 __attribute__((ext_vector_type(2)));
typedef _Float16 f16x8 __attribute__((ext_vector_type(8)));
typedef float    f32x4 __attribute__((ext_vector_type(4)));
typedef float    f32x2 __attribute__((ext_vector_type(2)));
typedef unsigned int u32x4 __attribute__((ext_vector_type(4)));

#define Bn 16
#define Cn 256
#define Hn 48
#define Wn 64
#define NDISP 21
#define SLAB 32768                      // bytes per (b,row) slab of in2, f16
#define WS_NEED ((size_t)Bn * Hn * SLAB)   // 25.2 MB

// ============================================================================
// Conversion kernel (in2 only), VERIFIED R5-R7: f32 [b][c][row][w] -> f16 ws
// slabs in MFMA-B-FRAGMENT order:
//   slab(b,row) offset = kc*8192 + par*4096 + ni*2048 + kk*1024 + g*256 + nl*16 + j*2
//   holds in2[b][c = kc*64 + kk*32 + g*8 + j][row][w = 2*(ni*16+nl) + par]
// ============================================================================
__global__ __launch_bounds__(256) void convert_kernel(const float* __restrict__ in2,
                                                      char* __restrict__ ws)
{
    int i = blockIdx.x;                         // 0..767
    int b = i / Hn, row = i % Hn;
    char* dslab = ws + (size_t)i * SLAB;
    int t  = threadIdx.x;
    int nl = t & 15, g = (t >> 4) & 3, kk = (t >> 6) & 1, ni = (t >> 7) & 1;
    int wq = ni * 16 + nl;                      // w' 0..31
    const float* srcb = in2 + ((size_t)b * Cn * Hn + row) * Wn;
    char* dbase = dslab + ni * 2048 + kk * 1024 + g * 256 + nl * 16;
    #pragma unroll
    for (int kc = 0; kc < 4; ++kc) {
        union { f16 h[8]; u32x4 u; } e0, e1;
        #pragma unroll
        for (int j = 0; j < 8; ++j) {
            int c = kc * 64 + kk * 32 + g * 8 + j;
            f32x2 v = *(const f32x2*)&srcb[(size_t)c * Hn * Wn + 2 * wq];
            e0.h[j] = (f16)v.x;                 // even w  (par 0)
            e1.h[j] = (f16)v.y;                 // odd  w  (par 1)
        }
        *(u32x4*)(dbase + kc * 8192)        = e0.u;
        *(u32x4*)(dbase + kc * 8192 + 4096) = e1.u;
    }
}

// ============================================================================
// Main kernel V10 = R7 (PASSING math, byte-identical indexing) with the
// barrier surgery its counters demanded: raw s_barrier + explicit counted
// waits instead of __syncthreads (whose compiler-emitted vmcnt(0) drain
// killed the depth-3 DMA pipeline every step -> MfmaUtil 7%).
//   barrier1: vmcnt(12) (own 4 loads x 3 newer stages -> row s arrived;
//             loads retire in order, stores only inflate) + lgkmcnt(0)
//             (prev step's bounce re-zero visible) + s_barrier.
//   barrier2: lgkmcnt(0) (scatter ds_writes visible to pair-partner; own
//             ds_reads retired -> ring-slot WAR safe) + s_barrier.
// sched_barrier(0) fences pin the compiler (rule #18).
// ============================================================================
__device__ __forceinline__ void stage4(const char* slab, char* slot, int off0, int l16)
{
    #pragma unroll
    for (int q = 0; q < 4; ++q) {
        int off = off0 + q * 1024 + l16;
        __builtin_amdgcn_global_load_lds((const AS1q void*)(slab + off),
                                         (AS3q void*)(slot + off), 16, 0, 0);
    }
}

__global__ __launch_bounds__(512, 2) void corr_mfma(const float* __restrict__ in1,
                                                    const char* __restrict__ ws,
                                                    float* __restrict__ out)
{
    __shared__ char  Bring[4][32768];           // row-slab ring (128 KB)
    __shared__ float bounce[4][1344];           // per-h [21 dx][64 w] planes (21 KB)

    const int tid = threadIdx.x;
    const int wv  = tid >> 6;
    const int l   = tid & 63;
    const int nl  = l & 15;
    const int g   = l >> 4;
    const int i   = wv >> 1;                    // h index 0..3
    const int p2  = wv & 1;                     // w parity

    int bid = blockIdx.x;
    int swz = (bid & 7) * 24 + (bid >> 3);      // 192 = 8*24, bijective XCD swizzle
    int b   = swz / 12;
    int rem = swz - b * 12;
    int pi  = rem / 6;
    int t   = rem - pi * 6;
    int h0  = pi + 8 * t;
    int h   = h0 + 2 * i;

    const float* in1b = in1 + (size_t)b * Cn * Hn * Wn;
    const char*  wsb  = ws  + (size_t)b * Hn * SLAB;
    float* outb = out + (size_t)b * (NDISP * NDISP) * Hn * Wn;

    int rlo = (h0 >= 20) ? (h0 - 20) : pi;      // parity-preserving clip
    int rhi = min(h0 + 26, 46 + pi);
    int NR  = ((rhi - rlo) >> 1) + 1;           // 14..22
    int dybase = (rlo - h0 + 20) >> 1;          // dy(s,i) = s + dybase - i

    // ---- zero invalid-dy planes for this h (dx split by parity wave) ----
    {
        int dylo = (h < 20) ? ((21 - h) >> 1) : 0;
        int dyhi = min(NDISP, ((67 - h) >> 1) + 1);
        f32x4 z = {0.f, 0.f, 0.f, 0.f};
        for (int dy = 0; dy < NDISP; ++dy) {
            if (dy >= dylo && dy < dyhi) continue;
            #pragma unroll
            for (int q = 0; q < 3; ++q) {
                int dx = p2 * 12 + q * 4 + g;
                if (dx < NDISP)
                    *(f32x4*)&outb[((size_t)(dy * NDISP + dx) * Hn + h) * Wn + nl * 4] = z;
            }
        }
    }

    // ---- A preload (VERIFIED frag contract): af[mi][k8] elem j =
    //      f16(in1[c=k8*32+g*8+j][h][w=2*(mi*16+nl)+p2]) ----
    f16x8 af[2][8];
    #pragma unroll
    for (int mi = 0; mi < 2; ++mi) {
        int wcol = 2 * (mi * 16 + nl) + p2;
        #pragma unroll
        for (int k8 = 0; k8 < 8; ++k8)
            #pragma unroll
            for (int j = 0; j < 8; ++j) {
                int c = k8 * 32 + g * 8 + j;
                af[mi][k8][j] = (f16)in1b[((size_t)c * Hn + h) * Wn + wcol];
            }
    }

    // ---- zero bounce planes ----
    {
        f32x4* bz = (f32x4*)&bounce[0][0];
        #pragma unroll
        for (int q = 0; q < 3; ++q) {
            int idx = q * 512 + tid;
            if (idx < 4 * 1344 / 4) bz[idx] = (f32x4){0.f, 0.f, 0.f, 0.f};
        }
    }

    asm volatile("s_waitcnt vmcnt(0)" ::: "memory");   // A-loads done; vmem queue known

    const int off0 = wv * 4096;                 // this wave's 4 KB staging share
    const int l16  = l * 16;

    // ---- prologue: stage rows 0..2 into slots 0..2 ----
    #pragma unroll
    for (int ps = 0; ps < 3; ++ps)
        stage4(wsb + (size_t)(rlo + 2 * min(ps, NR - 1)) * SLAB, &Bring[ps][0], off0, l16);

    for (int s = 0; s < NR; ++s) {
        // phase A: stage row s+3 (clamped dummy at tail keeps vmcnt uniform)
        stage4(wsb + (size_t)(rlo + 2 * min(s + 3, NR - 1)) * SLAB,
               &Bring[(s + 3) & 3][0], off0, l16);
        // barrier1: counted vmcnt keeps the DMA queue ALIVE across the barrier
        __builtin_amdgcn_sched_barrier(0);
        asm volatile("s_waitcnt vmcnt(12) lgkmcnt(0)" ::: "memory");
        __builtin_amdgcn_s_barrier();
        __builtin_amdgcn_sched_barrier(0);

        int dy = s + dybase - i;
        bool valid = (unsigned)dy < (unsigned)NDISP;
        const char* slot = &Bring[s & 3][0];
        float* bp = &bounce[i][0];

        if (valid) {
            f32x4 acc[2][2];                    // [mi][ni]
            acc[0][0] = acc[0][1] = acc[1][0] = acc[1][1] = (f32x4){0.f, 0.f, 0.f, 0.f};
            #pragma unroll
            for (int k8 = 0; k8 < 8; ++k8) {
                const char* kb = slot + (k8 >> 1) * 8192 + (k8 & 1) * 1024 + p2 * 4096;
                f16x8 b0 = *(const f16x8*)(kb + l16);
                f16x8 b1 = *(const f16x8*)(kb + 2048 + l16);
                #pragma unroll
                for (int mi = 0; mi < 2; ++mi) {
                    acc[mi][0] = __builtin_amdgcn_mfma_f32_16x16x32_f16(af[mi][k8], b0, acc[mi][0], 0, 0, 0);
                    acc[mi][1] = __builtin_amdgcn_mfma_f32_16x16x32_f16(af[mi][k8], b1, acc[mi][1], 0, 0, 0);
                }
            }
            // scatter diag band into pair-shared bounce (w XOR-swizzled per dx)
            #pragma unroll
            for (int mi = 0; mi < 2; ++mi)
                #pragma unroll
                for (int ni = 0; ni < 2; ++ni)
                    #pragma unroll
                    for (int rr = 0; rr < 4; ++rr) {
                        int o = nl + ((ni - mi) << 4) - 4 * g - rr;   // dx - 10
                        if (o >= -10 && o <= 10) {
                            int m  = mi * 16 + 4 * g + rr;
                            int dx = o + 10;
                            int wsw = (2 * m + p2) ^ ((dx & 7) << 3);
                            bp[dx * 64 + wsw] = acc[mi][ni][rr];
                        }
                    }
        }
        // barrier2: LDS-only wait (scatter visible; ds_reads retired -> ring
        // slot free for the next stage); vmem queue untouched.
        __builtin_amdgcn_sched_barrier(0);
        asm volatile("s_waitcnt lgkmcnt(0)" ::: "memory");
        __builtin_amdgcn_s_barrier();
        __builtin_amdgcn_sched_barrier(0);

        if (valid) {
            #pragma unroll
            for (int q = 0; q < 3; ++q) {
                int dx = p2 * 12 + q * 4 + g;
                if (dx < NDISP) {
                    int wb = (4 * nl) ^ ((dx & 7) << 3);
                    f32x4 v = *(f32x4*)&bp[dx * 64 + wb];
                    v = v * (1.0f / 256.0f);
                    *(f32x4*)&outb[((size_t)(dy * NDISP + dx) * Hn + h) * Wn + nl * 4] = v;
                    *(f32x4*)&bp[dx * 64 + wb] = (f32x4){0.f, 0.f, 0.f, 0.f};  // re-zero
                }
            }
        }
    }
}

// ============================================================================
// Fallback (round-1 kernel, known-good) if ws_size is too small.
// ============================================================================
#define BDIM 384
#define C2T  8
#define NCHUNK 16
#define JJN  56
#define IN1_DW (2*128*32)
#define IN2_DW (128*JJN + 64)

__device__ __forceinline__ unsigned int packh2(float a, float b) {
    union { f16x2 h; unsigned int u; } u;
    u.h.x = (_Float16)a; u.h.y = (_Float16)b;
    return u.u;
}
__device__ __forceinline__ float dot2(unsigned int a, unsigned int b, float c) {
    union { unsigned int u; f16x2 h; } ua, ub;
    ua.u = a; ub.u = b;
#if HAVE_FDOT2
    return __builtin_amdgcn_fdot2(ua.h, ub.h, c, false);
#else
    return c + (float)ua.h.x * (float)ub.h.x + (float)ua.h.y * (float)ub.h.y;
#endif
}
__device__ __forceinline__ int in2row(int m) { return m * JJN + (((m >> 3) & 1) << 2); }

__global__ __launch_bounds__(BDIM, 3) void corr_fallback(
    const float* __restrict__ in1, const float* __restrict__ in2,
    float* __restrict__ out)
{
    __shared__ __align__(16) unsigned int s_in1[IN1_DW];
    __shared__ __align__(16) unsigned int s_in2[IN2_DW];
    const int tid = threadIdx.x;
    int bid = blockIdx.x;
    int sw  = (bid & 7) * 96 + (bid >> 3);
    const int b = sw / Hn;
    const int h = sw - b * Hn;
    int dylo = (h < 20) ? ((21 - h) >> 1) : 0;
    int dyhi = min(NDISP - 1, (67 - h) >> 1) + 1;
    const int V = dyhi - dylo;
    const int wg   = tid & 15;
    const int p    = wg & 1;
    const int widx = (wg >> 1) << 2;
    const int t2   = tid >> 4;
    const int dxg  = t2 % 3;
    const int slot = t2 / 3;
    const int dxb  = dxg << 3;
    const float* in1b = in1 + (size_t)b * Cn * Hn * Wn;
    const float* in2b = in2 + (size_t)b * Cn * Hn * Wn;
    float* outb = out + (size_t)b * (NDISP * NDISP) * Hn * Wn;
    {
        int nz = NDISP - V;
        for (int j = tid; j < nz * NDISP * Wn; j += BDIM) {
            int zi  = j / (NDISP * Wn);
            int rem = j - zi * (NDISP * Wn);
            int dy  = (zi < dylo) ? zi : (dyhi + (zi - dylo));
            int dx  = rem >> 6;
            int w   = rem & 63;
            outb[((size_t)(dy * NDISP + dx) * Hn + h) * Wn + w] = 0.0f;
        }
    }
    for (int i = tid; i < 64 * 128; i += BDIM) {
        int w  = i & 63;
        int c2 = i >> 6;
        float f0 = in1b[((size_t)(2 * c2)     * Hn + h) * Wn + w];
        float f1 = in1b[((size_t)(2 * c2 + 1) * Hn + h) * Wn + w];
        int pp = w & 1, wq = w >> 1;
        s_in1[(pp * 128 + c2) * 32 + wq] = packh2(f0, f1);
    }
    const int nR = (V + 7) >> 3;
    for (int round = 0; round < nR; ++round) {
        const int dy0   = dylo + (round << 3);
        const int mydy  = dy0 + slot;
        const bool valid = (mydy < dyhi);
        float acc[4][8];
        #pragma unroll
        for (int i = 0; i < 4; ++i)
            #pragma unroll
            for (int j = 0; j < 8; ++j) acc[i][j] = 0.0f;
        for (int ch = 0; ch < NCHUNK; ++ch) {
            const int c2b = ch * C2T;
            __syncthreads();
            for (int i = tid; i < 8 * 2 * C2T * 112 / 2; i += BDIM) {
                int jj2 = i % 112;
                int t   = i / 112;
                int pp  = jj2 & 1;
                int jj  = jj2 >> 1;
                int c2o = t % C2T;
                int sl  = t / C2T;
                int dy  = dy0 + sl;
                if (dy >= dyhi) continue;
                int w2  = jj2 - 20;
                unsigned int val = 0;
                if (w2 >= 0 && w2 < Wn) {
                    int rr = h + 2 * dy - 20;
                    int c = 2 * (c2b + c2o);
                    const float* srcp = &in2b[((size_t)c * Hn + rr) * Wn + w2];
                    val = packh2(srcp[0], srcp[Hn * Wn]);
                }
                s_in2[in2row((sl * 2 + pp) * C2T + c2o) + jj] = val;
            }
            __syncthreads();
            if (valid) {
                const int base1 = (p * 128 + c2b) * 32 + widx;
                #pragma unroll
                for (int c2o = 0; c2o < C2T; ++c2o) {
                    u32x4 a4 = *(const u32x4*)&s_in1[base1 + c2o * 32];
                    const unsigned int* vr =
                        &s_in2[in2row((slot * 2 + p) * C2T + c2o) + widx + dxb];
                    u32x4 v0 = *(const u32x4*)(vr);
                    u32x4 v1 = *(const u32x4*)(vr + 4);
                    u32x4 v2 = *(const u32x4*)(vr + 8);
                    unsigned int av[4]  = {a4.x, a4.y, a4.z, a4.w};
                    unsigned int vv[12] = {v0.x, v0.y, v0.z, v0.w,
                                           v1.x, v1.y, v1.z, v1.w,
                                           v2.x, v2.y, v2.z, v2.w};
                    #pragma unroll
                    for (int wi = 0; wi < 4; ++wi)
                        #pragma unroll
                        for (int di = 0; di < 8; ++di)
                            acc[wi][di] = dot2(av[wi], vv[wi + di], acc[wi][di]);
                }
            }
        }
        float* s_out = (float*)s_in2;
        for (int half = 0; half < 2; ++half) {
            __syncthreads();
            if (((slot >> 2) == half) && valid) {
                #pragma unroll
                for (int wi = 0; wi < 4; ++wi)
                    #pragma unroll
                    for (int di = 0; di < 8; ++di) {
                        int dx = dxb + di;
                        if (dx < NDISP) {
                            int w = p + ((widx + wi) << 1);
                            s_out[(((slot & 3) * NDISP + dx) << 6) + w] =
                                acc[wi][di] * (1.0f / 256.0f);
                        }
                    }
            }
            __syncthreads();
            int dyb = dy0 + (half << 2);
            for (int j = tid; j < 4 * NDISP * Wn; j += BDIM) {
                int s  = j / (NDISP * Wn);
                int dy = dyb + s;
                if (dy < dyhi) {
                    int rem = j - s * (NDISP * Wn);
                    int dx  = rem >> 6;
                    int w   = rem & 63;
                    outb[((size_t)(dy * NDISP + dx) * Hn + h) * Wn + w] = s_out[j];
                }
            }
        }
    }
}

extern "C" void kernel_launch(void* const* d_in, const int* in_sizes, int n_in,
                              void* d_out, int out_size, void* d_ws, size_t ws_size,
                              hipStream_t stream) {
    (void)in_sizes; (void)n_in; (void)out_size;
    const float* in1 = (const float*)d_in[0];
    const float* in2 = (const float*)d_in[1];
    float* out = (float*)d_out;
    if (ws_size >= WS_NEED) {
        convert_kernel<<<dim3(Bn * Hn), dim3(256), 0, stream>>>(in2, (char*)d_ws);
        corr_mfma<<<dim3(192), dim3(512), 0, stream>>>(in1, (const char*)d_ws, out);
    } else {
        corr_fallback<<<dim3(Bn * Hn), dim3(BDIM), 0, stream>>>(in1, in2, out);
    }
}